// Round 8
// baseline (146.369 us; speedup 1.0000x reference)
//
#include <hip/hip_runtime.h>
#include <hip/hip_bf16.h>

typedef __hip_bfloat16 bf16;
typedef __bf16 bf16x8 __attribute__((ext_vector_type(8)));
typedef float f32x4 __attribute__((ext_vector_type(4)));
typedef unsigned short u16x8 __attribute__((ext_vector_type(8)));

#define B_SZ   4
#define T_SEQ  2048
#define D_IN   1024
#define D_QKV  64
#define BT     (B_SZ * T_SEQ)   // 8192 rows
#define PSTR   72               // attn p-tile LDS row stride (+8 pad, 16B rows)
#define KSPL   4                // attention K-split ways (waves per block)

// ---------------------------------------------------------------------------
// Kernel 0: W transpose/convert via LDS, coalesced. 48 blocks: 16 per matrix,
// each handles 64 k-rows. Wt[n][k] bf16, n = 0..191 over [Wq|Wk|Wv].
// ---------------------------------------------------------------------------
__global__ __launch_bounds__(256) void wt_prep(
    const float* __restrict__ Wq, const float* __restrict__ Wk,
    const float* __restrict__ Wv, bf16* __restrict__ wt)
{
    __shared__ float ws[64 * 65];
    const int bx = blockIdx.x;
    const int m  = bx >> 4;
    const int k0 = (bx & 15) << 6;
    const float* W = (m == 0) ? Wq : (m == 1) ? Wk : Wv;
    const int tid = threadIdx.x;
    #pragma unroll
    for (int i = 0; i < 16; ++i) {
        const int idx = i * 256 + tid;          // coalesced over n
        const int kk = idx >> 6, nn = idx & 63;
        ws[kk * 65 + nn] = W[(size_t)(k0 + kk) * D_QKV + nn];
    }
    __syncthreads();
    const int n = tid >> 2, kq = (tid & 3) << 4;
    bf16 tmp[16];
    #pragma unroll
    for (int j = 0; j < 16; ++j)
        tmp[j] = __float2bfloat16(ws[(kq + j) * 65 + n]);
    uint4* dst = (uint4*)(wt + (size_t)(m * 64 + n) * D_IN + k0 + kq);
    dst[0] = ((uint4*)tmp)[0];
    dst[1] = ((uint4*)tmp)[1];
}

// ---------------------------------------------------------------------------
// Kernel A: QKV projection MFMA GEMM, B-sharing tiling. 512 blocks =
// 128 m-groups x 4 n-groups. All 4 waves of a block use the SAME 3 n-tiles
// (B lines L1-shared) and disjoint 16-row m-sub-tiles (A read once/wave).
// L2 traffic ~176 MB vs 1.3 GB for the old per-wave-private tiling.
// Register pipeline: A (L2/L3) distance 2, B (L1) distance 1.
// ---------------------------------------------------------------------------
__global__ __launch_bounds__(256, 2) void qkv_proj_mfma(
    const float* __restrict__ x, const bf16* __restrict__ wt,
    bf16* __restrict__ qb, bf16* __restrict__ kb, bf16* __restrict__ vt)
{
    const int tid  = threadIdx.x;
    const int wave = tid >> 6;
    const int lane = tid & 63;
    const int col  = lane & 15;
    const int quad = lane >> 4;
    const int bx   = blockIdx.x;
    const size_t rowbase = (size_t)(bx >> 2) * 64 + wave * 16;  // wave's m-tile
    const int nt0 = (bx & 3) * 3;                               // block's n-group

    const float4* xr  = (const float4*)(x + (rowbase + col) * D_IN);  // 256 f4/row
    const uint4*  wt4 = (const uint4*)wt;                             // 128 u4/n-row

    f32x4 acc[3];
    #pragma unroll
    for (int i = 0; i < 3; ++i) acc[i] = (f32x4){0.f, 0.f, 0.f, 0.f};

    float4 a[3][4];   // A ring, distance-2 prefetch
    uint4  b[2][6];   // B ring, distance-1 prefetch

    // prologue: A iters 0,1; B iter 0
    #pragma unroll
    for (int p = 0; p < 2; ++p)
        #pragma unroll
        for (int h = 0; h < 2; ++h) {
            a[p][h * 2]     = xr[p * 16 + h * 8 + quad * 2];
            a[p][h * 2 + 1] = xr[p * 16 + h * 8 + quad * 2 + 1];
        }
    #pragma unroll
    for (int i = 0; i < 3; ++i) {
        const size_t n = (size_t)((nt0 + i) * 16 + col) * 128;
        b[0][i * 2]     = wt4[n + quad];
        b[0][i * 2 + 1] = wt4[n + 4 + quad];
    }

    #pragma unroll
    for (int it = 0; it < 16; ++it) {
        if (it + 2 < 16) {                    // prefetch A for iter it+2
            const int kofs = (it + 2) * 16;
            #pragma unroll
            for (int h = 0; h < 2; ++h) {
                a[(it + 2) % 3][h * 2]     = xr[kofs + h * 8 + quad * 2];
                a[(it + 2) % 3][h * 2 + 1] = xr[kofs + h * 8 + quad * 2 + 1];
            }
        }
        if (it + 1 < 16) {                    // prefetch B for iter it+1
            #pragma unroll
            for (int i = 0; i < 3; ++i) {
                const size_t n = (size_t)((nt0 + i) * 16 + col) * 128 + (it + 1) * 8;
                b[(it + 1) & 1][i * 2]     = wt4[n + quad];
                b[(it + 1) & 1][i * 2 + 1] = wt4[n + 4 + quad];
            }
        }
        __builtin_amdgcn_sched_barrier(0);    // don't sink the prefetches
        #pragma unroll
        for (int h = 0; h < 2; ++h) {
            const float4 a0 = a[it % 3][h * 2], a1 = a[it % 3][h * 2 + 1];
            const bf16x8 af = (bf16x8){(__bf16)a0.x, (__bf16)a0.y, (__bf16)a0.z, (__bf16)a0.w,
                                       (__bf16)a1.x, (__bf16)a1.y, (__bf16)a1.z, (__bf16)a1.w};
            #pragma unroll
            for (int i = 0; i < 3; ++i)
                acc[i] = __builtin_amdgcn_mfma_f32_16x16x32_bf16(
                             af, __builtin_bit_cast(bf16x8, b[it & 1][i * 2 + h]), acc[i], 0, 0, 0);
        }
    }

    // epilogue: q/k row-major, v transposed
    const int bb = (int)(rowbase >> 11);
    const int t0 = (int)(rowbase & (T_SEQ - 1));
    #pragma unroll
    for (int i = 0; i < 3; ++i) {
        const int ntile = nt0 + i;
        const int n = ntile * 16 + col;
        if (ntile < 4) {
            #pragma unroll
            for (int r = 0; r < 4; ++r)
                qb[(rowbase + quad * 4 + r) * D_QKV + n] = __float2bfloat16(acc[i][r]);
        } else if (ntile < 8) {
            #pragma unroll
            for (int r = 0; r < 4; ++r)
                kb[(rowbase + quad * 4 + r) * D_QKV + (n - 64)] = __float2bfloat16(acc[i][r]);
        } else {
            #pragma unroll
            for (int r = 0; r < 4; ++r)
                vt[(size_t)bb * D_QKV * T_SEQ + (size_t)(n - 128) * T_SEQ + t0 + quad * 4 + r] =
                    __float2bfloat16(acc[i][r]);
        }
    }
}

// ---------------------------------------------------------------------------
// Kernel B: MFMA flash attention, no-max softmax (scores bounded), 4-way
// K-split per 256-thread block: wave w takes chunks c%4==w, linear combine
// in LDS. 512 blocks x 4 waves.
// ---------------------------------------------------------------------------
__global__ __launch_bounds__(256) void attn_kernel(
    const bf16* __restrict__ qb, const bf16* __restrict__ kb,
    const bf16* __restrict__ vt, float* __restrict__ out)
{
    __shared__ unsigned short plds[KSPL * 16 * PSTR];  // 9 KB per-wave P tiles
    __shared__ float os[KSPL][16][64];                 // 16 KB per-wave O
    __shared__ float lw[KSPL][16];                     // per-wave l

    const int tid  = threadIdx.x;
    const int wave = tid >> 6;
    const int lane = tid & 63;
    const int col  = lane & 15;
    const int quad = lane >> 4;
    const int tl   = blockIdx.x;
    const int b    = tl >> 7;
    const int qw   = (127 - (tl & 127)) << 4;          // heavy tiles first
    const int nch  = (qw >> 6) + 1;

    const uint4* q4 = (const uint4*)(qb + (size_t)b * T_SEQ * D_QKV);
    const uint4* k4 = (const uint4*)(kb + (size_t)b * T_SEQ * D_QKV);
    const uint4* v4 = (const uint4*)(vt + (size_t)b * D_QKV * T_SEQ);

    const bf16x8 aq0 = __builtin_bit_cast(bf16x8, q4[(qw + col) * 8 + quad]);
    const bf16x8 aq1 = __builtin_bit_cast(bf16x8, q4[(qw + col) * 8 + 4 + quad]);

    f32x4 o[4];
    float ls[4];
    #pragma unroll
    for (int dt = 0; dt < 4; ++dt) o[dt] = (f32x4){0.f, 0.f, 0.f, 0.f};
    #pragma unroll
    for (int r = 0; r < 4; ++r) ls[r] = 0.f;

    unsigned short* pl = plds + wave * 16 * PSTR;
    const u16x8* p8 = (const u16x8*)pl;

    for (int c = wave; c < nch; c += KSPL) {
        const int kbase = c << 6;

        // V for this chunk (issued early, consumed after softmax)
        bf16x8 bv0[4], bv1[4];
        #pragma unroll
        for (int dt = 0; dt < 4; ++dt) {
            bv0[dt] = __builtin_bit_cast(bf16x8, v4[(dt * 16 + col) * 256 + (kbase >> 3) + quad]);
            bv1[dt] = __builtin_bit_cast(bf16x8, v4[(dt * 16 + col) * 256 + (kbase >> 3) + 4 + quad]);
        }

        // QK^T
        f32x4 sc[4];
        #pragma unroll
        for (int nt = 0; nt < 4; ++nt) {
            const int krow = kbase + nt * 16 + col;
            const bf16x8 bk0 = __builtin_bit_cast(bf16x8, k4[krow * 8 + quad]);
            const bf16x8 bk1 = __builtin_bit_cast(bf16x8, k4[krow * 8 + 4 + quad]);
            sc[nt] = (f32x4){0.f, 0.f, 0.f, 0.f};
            sc[nt] = __builtin_amdgcn_mfma_f32_16x16x32_bf16(aq0, bk0, sc[nt], 0, 0, 0);
            sc[nt] = __builtin_amdgcn_mfma_f32_16x16x32_bf16(aq1, bk1, sc[nt], 0, 0, 0);
        }

        // causal mask (only the final chunk can contain k > q)
        if (c == nch - 1) {
            #pragma unroll
            for (int nt = 0; nt < 4; ++nt) {
                const int kp = kbase + nt * 16 + col;
                #pragma unroll
                for (int r = 0; r < 4; ++r)
                    if (kp > qw + quad * 4 + r) sc[nt][r] = -INFINITY;
            }
        }

        // P = exp(s/8) raw (no max subtraction; scores bounded); per-lane l
        #pragma unroll
        for (int nt = 0; nt < 4; ++nt) {
            #pragma unroll
            for (int r = 0; r < 4; ++r) {
                const float pv = __expf(sc[nt][r] * 0.125f);
                ls[r] += pv;
                pl[(quad * 4 + r) * PSTR + nt * 16 + col] =
                    __builtin_bit_cast(unsigned short, __float2bfloat16(pv));
            }
        }

        // P A-fragments from LDS (same-wave RAW; lgkmcnt handles it)
        const bf16x8 pa0 = __builtin_bit_cast(bf16x8, p8[col * 9 + quad]);
        const bf16x8 pa1 = __builtin_bit_cast(bf16x8, p8[col * 9 + 4 + quad]);

        // O += P * V
        #pragma unroll
        for (int dt = 0; dt < 4; ++dt) {
            o[dt] = __builtin_amdgcn_mfma_f32_16x16x32_bf16(pa0, bv0[dt], o[dt], 0, 0, 0);
            o[dt] = __builtin_amdgcn_mfma_f32_16x16x32_bf16(pa1, bv1[dt], o[dt], 0, 0, 0);
        }
    }

    // single post-loop l reduction over the 16 key-lanes
    #pragma unroll
    for (int r = 0; r < 4; ++r) {
        #pragma unroll
        for (int msk = 1; msk < 16; msk <<= 1)
            ls[r] += __shfl_xor(ls[r], msk);
    }
    if (col == 0) {
        #pragma unroll
        for (int r = 0; r < 4; ++r) lw[wave][quad * 4 + r] = ls[r];
    }
    #pragma unroll
    for (int dt = 0; dt < 4; ++dt)
        #pragma unroll
        for (int r = 0; r < 4; ++r)
            os[wave][quad * 4 + r][dt * 16 + col] = o[dt][r];
    __syncthreads();

    // combine KSPL partial (O, l) and store
    #pragma unroll
    for (int i = 0; i < 4; ++i) {
        const int idx = i * 256 + tid;
        const int q = idx >> 6, d = idx & 63;
        float s = 0.f, l = 0.f;
        #pragma unroll
        for (int w = 0; w < KSPL; ++w) { s += os[w][q][d]; l += lw[w][q]; }
        out[((size_t)b * T_SEQ + qw + q) * D_QKV + d] = s / l;
    }
}

// ---------------------------------------------------------------------------
extern "C" void kernel_launch(void* const* d_in, const int* in_sizes, int n_in,
                              void* d_out, int out_size, void* d_ws, size_t ws_size,
                              hipStream_t stream) {
    const float* x  = (const float*)d_in[0];
    const float* Wq = (const float*)d_in[1];
    const float* Wk = (const float*)d_in[2];
    const float* Wv = (const float*)d_in[3];
    float* out = (float*)d_out;

    bf16* qb = (bf16*)d_ws;                       // 1 MB
    bf16* kb = qb + (size_t)BT * D_QKV;           // 1 MB
    bf16* vt = kb + (size_t)BT * D_QKV;           // 1 MB
    bf16* wt = vt + (size_t)BT * D_QKV;           // 384 KB

    wt_prep<<<48, 256, 0, stream>>>(Wq, Wk, Wv, wt);
    qkv_proj_mfma<<<512, 256, 0, stream>>>(x, wt, qb, kb, vt);
    attn_kernel<<<BT / 16, 256, 0, stream>>>(qb, kb, vt, out);
}

// Round 9
// 110.131 us; speedup vs baseline: 1.3291x; 1.3291x over previous
//
#include <hip/hip_runtime.h>
#include <hip/hip_bf16.h>

typedef __hip_bfloat16 bf16;
typedef __bf16 bf16x8 __attribute__((ext_vector_type(8)));
typedef float f32x4 __attribute__((ext_vector_type(4)));
typedef unsigned short u16x8 __attribute__((ext_vector_type(8)));

#define B_SZ   4
#define T_SEQ  2048
#define D_IN   1024
#define D_QKV  64
#define BT     (B_SZ * T_SEQ)   // 8192 rows
#define PSTR   72               // attn p-tile LDS row stride (+8 pad, 16B rows)

// async global->LDS DMA, 16B per lane; LDS dest = uniform base + lane*16
#define GLD_LDS(gp, lp) __builtin_amdgcn_global_load_lds(                     \
    (const __attribute__((address_space(1))) void*)(gp),                      \
    (__attribute__((address_space(3))) void*)(lp), 16, 0, 0)

// ---------------------------------------------------------------------------
// Kernel 0: W transpose/convert via LDS, coalesced. Wt[n][k] bf16, n=0..191.
// ---------------------------------------------------------------------------
__global__ __launch_bounds__(256) void wt_prep(
    const float* __restrict__ Wq, const float* __restrict__ Wk,
    const float* __restrict__ Wv, bf16* __restrict__ wt)
{
    __shared__ float ws[64 * 65];
    const int bx = blockIdx.x;
    const int m  = bx >> 4;
    const int k0 = (bx & 15) << 6;
    const float* W = (m == 0) ? Wq : (m == 1) ? Wk : Wv;
    const int tid = threadIdx.x;
    #pragma unroll
    for (int i = 0; i < 16; ++i) {
        const int idx = i * 256 + tid;
        const int kk = idx >> 6, nn = idx & 63;
        ws[kk * 65 + nn] = W[(size_t)(k0 + kk) * D_QKV + nn];
    }
    __syncthreads();
    const int n = tid >> 2, kq = (tid & 3) << 4;
    bf16 tmp[16];
    #pragma unroll
    for (int j = 0; j < 16; ++j)
        tmp[j] = __float2bfloat16(ws[(kq + j) * 65 + n]);
    uint4* dst = (uint4*)(wt + (size_t)(m * 64 + n) * D_IN + k0 + kq);
    dst[0] = ((uint4*)tmp)[0];
    dst[1] = ((uint4*)tmp)[1];
}

// ---------------------------------------------------------------------------
// Kernel A: QKV projection MFMA GEMM with LDS-staged operands (dedup across
// waves -> minimal per-CU vmem-pipe bytes). 256 blocks = 128 m-groups(64 rows)
// x 2 n-groups(96 cols). K-steps of 64, double-buffered global_load_lds.
// LDS layouts (swizzled chunk index to kill ds_read bank conflicts):
//   As[64 m][16 ch16B] fp32, phys_ch = (ch + m) & 15
//   Bs[96 n][ 8 ch16B] bf16, phys_ch = (ch + n) & 7
// ---------------------------------------------------------------------------
__global__ __launch_bounds__(256) void qkv_proj_mfma(
    const float* __restrict__ x, const bf16* __restrict__ wt,
    bf16* __restrict__ qb, bf16* __restrict__ kb, bf16* __restrict__ vt)
{
    __shared__ uint4 As[2][1024];   // 2 x 16 KB
    __shared__ uint4 Bs[2][768];    // 2 x 12 KB

    const int tid  = threadIdx.x;
    const int wave = tid >> 6;
    const int lane = tid & 63;
    const int col  = lane & 15;
    const int quad = lane >> 4;
    const int bx   = blockIdx.x;
    const int m0   = (bx >> 1) * 64;
    const int ng   = bx & 1;

    f32x4 acc[6];
    #pragma unroll
    for (int i = 0; i < 6; ++i) acc[i] = (f32x4){0.f, 0.f, 0.f, 0.f};

    auto stage = [&](int it, int buf) {
        const int k0 = it * 64;
        #pragma unroll
        for (int j = 0; j < 7; ++j) {
            const int s = wave + j * 4;          // wave-uniform slot
            if (s < 16) {                        // A: 16 slots x 1KB
                const int c = s * 64 + lane;
                const int r = c >> 4;
                const int ccl = ((c & 15) - r) & 15;
                const float* g = x + (size_t)(m0 + r) * D_IN + k0 + ccl * 4;
                GLD_LDS(g, &As[buf][s * 64]);
            } else {                             // B: 12 slots x 1KB
                const int bs = s - 16;
                const int c = bs * 64 + lane;
                const int n = c >> 3;
                const int ccl = ((c & 7) - n) & 7;
                const bf16* g = wt + (size_t)(ng * 96 + n) * D_IN + k0 + ccl * 8;
                GLD_LDS(g, &Bs[buf][bs * 64]);
            }
        }
    };

    stage(0, 0);
    const int r = wave * 16 + col;               // this lane's A row (local)
    #pragma unroll 1
    for (int it = 0; it < 16; ++it) {
        __syncthreads();                         // staging(it) done, buf free
        if (it + 1 < 16) stage(it + 1, (it + 1) & 1);   // DMA overlaps compute
        const float4* Ac = (const float4*)As[it & 1];
        const uint4*  Bc = Bs[it & 1];
        #pragma unroll
        for (int s = 0; s < 2; ++s) {
            const int ca = s * 8 + quad * 2;
            const float4 a0 = Ac[r * 16 + ((ca + r) & 15)];
            const float4 a1 = Ac[r * 16 + ((ca + 1 + r) & 15)];
            const bf16x8 af = (bf16x8){(__bf16)a0.x, (__bf16)a0.y, (__bf16)a0.z, (__bf16)a0.w,
                                       (__bf16)a1.x, (__bf16)a1.y, (__bf16)a1.z, (__bf16)a1.w};
            #pragma unroll
            for (int i = 0; i < 6; ++i) {
                const int n = i * 16 + col;
                const bf16x8 bfr = __builtin_bit_cast(bf16x8,
                    Bc[n * 8 + ((s * 4 + quad + n) & 7)]);
                acc[i] = __builtin_amdgcn_mfma_f32_16x16x32_bf16(af, bfr, acc[i], 0, 0, 0);
            }
        }
    }

    // epilogue: q/k row-major bf16, v transposed bf16
    const int bb = m0 >> 11;
    const int tl = m0 & (T_SEQ - 1);
    #pragma unroll
    for (int i = 0; i < 6; ++i) {
        const int n = ng * 96 + i * 16 + col;
        #pragma unroll
        for (int rr = 0; rr < 4; ++rr) {
            const int row = m0 + wave * 16 + quad * 4 + rr;
            const bf16 vq = __float2bfloat16(acc[i][rr]);
            if (n < 64)       qb[(size_t)row * D_QKV + n] = vq;
            else if (n < 128) kb[(size_t)row * D_QKV + (n - 64)] = vq;
            else              vt[(size_t)bb * D_QKV * T_SEQ + (size_t)(n - 128) * T_SEQ
                                 + (tl + wave * 16 + quad * 4 + rr)] = vq;
        }
    }
}

// ---------------------------------------------------------------------------
// Kernel B: MFMA flash attention, LDS-staged K/V shared by all 4 waves
// (64 q-rows per block), no-max softmax (scores bounded -> linear partials),
// 4-way chunk split across blocks. 512 blocks; balanced heavy+light pairing:
// bx<256 -> tile 127-(bx>>2), else tile (bx-256)>>2; quarter = bx&3.
// LDS: Ks[64 key][8 ch] / Vs[64 d][8 ch] bf16, phys_ch = (ch + row) & 7.
// ---------------------------------------------------------------------------
__global__ __launch_bounds__(256) void attn_kernel(
    const bf16* __restrict__ qb, const bf16* __restrict__ kb,
    const bf16* __restrict__ vt, float* __restrict__ Op, float* __restrict__ lp)
{
    __shared__ uint4 Ks[2][512];                 // 2 x 8 KB
    __shared__ uint4 Vs[2][512];                 // 2 x 8 KB
    __shared__ unsigned short plds[4 * 16 * PSTR];

    const int tid  = threadIdx.x;
    const int wave = tid >> 6;
    const int lane = tid & 63;
    const int col  = lane & 15;
    const int quad = lane >> 4;
    const int bx   = blockIdx.x;
    const int tile    = (bx < 256) ? (127 - (bx >> 2)) : ((bx - 256) >> 2);
    const int quarter = bx & 3;
    const int b    = tile >> 5;
    const int qloc = (tile & 31) * 64;           // q start within batch
    const int nch  = (tile & 31) + 1;            // causal chunk count

    const bf16* kbp = kb + (size_t)b * T_SEQ * D_QKV;
    const bf16* vtp = vt + (size_t)b * D_QKV * T_SEQ;
    const uint4* q4 = (const uint4*)(qb + (size_t)b * T_SEQ * D_QKV);

    const bf16x8 aq0 = __builtin_bit_cast(bf16x8, q4[(qloc + wave * 16 + col) * 8 + quad]);
    const bf16x8 aq1 = __builtin_bit_cast(bf16x8, q4[(qloc + wave * 16 + col) * 8 + 4 + quad]);

    f32x4 o[4];
    float ls[4];
    #pragma unroll
    for (int dt = 0; dt < 4; ++dt) o[dt] = (f32x4){0.f, 0.f, 0.f, 0.f};
    #pragma unroll
    for (int rr = 0; rr < 4; ++rr) ls[rr] = 0.f;

    unsigned short* pl = plds + wave * 16 * PSTR;
    const u16x8* p8 = (const u16x8*)pl;

    auto stage = [&](int c, int buf) {
        const int kb0 = c * 64;
        #pragma unroll
        for (int j = 0; j < 4; ++j) {
            const int s = wave + j * 4;
            if (s < 8) {                         // K: 8 slots
                const int ch = s * 64 + lane;
                const int key = ch >> 3;
                const int ccl = ((ch & 7) - key) & 7;
                const bf16* g = kbp + (size_t)(kb0 + key) * D_QKV + ccl * 8;
                GLD_LDS(g, &Ks[buf][s * 64]);
            } else {                             // V: 8 slots
                const int vs = s - 8;
                const int ch = vs * 64 + lane;
                const int d = ch >> 3;
                const int ccl = ((ch & 7) - d) & 7;
                const bf16* g = vtp + (size_t)d * T_SEQ + kb0 + ccl * 8;
                GLD_LDS(g, &Vs[buf][vs * 64]);
            }
        }
    };

    if (quarter < nch) stage(quarter, 0);
    int i = 0;
    for (int c = quarter; c < nch; c += 4, ++i) {
        __syncthreads();
        if (c + 4 < nch) stage(c + 4, (i + 1) & 1);
        const uint4* Kc = Ks[i & 1];
        const uint4* Vc = Vs[i & 1];

        // QK^T from LDS K
        f32x4 sc[4];
        #pragma unroll
        for (int nt = 0; nt < 4; ++nt) {
            const int kp = nt * 16 + col;
            const bf16x8 bk0 = __builtin_bit_cast(bf16x8, Kc[kp * 8 + ((quad + kp) & 7)]);
            const bf16x8 bk1 = __builtin_bit_cast(bf16x8, Kc[kp * 8 + ((4 + quad + kp) & 7)]);
            sc[nt] = (f32x4){0.f, 0.f, 0.f, 0.f};
            sc[nt] = __builtin_amdgcn_mfma_f32_16x16x32_bf16(aq0, bk0, sc[nt], 0, 0, 0);
            sc[nt] = __builtin_amdgcn_mfma_f32_16x16x32_bf16(aq1, bk1, sc[nt], 0, 0, 0);
        }

        // causal mask (only the diagonal chunk)
        if (c == nch - 1) {
            #pragma unroll
            for (int nt = 0; nt < 4; ++nt) {
                const int kp = c * 64 + nt * 16 + col;
                #pragma unroll
                for (int rr = 0; rr < 4; ++rr)
                    if (kp > qloc + wave * 16 + quad * 4 + rr) sc[nt][rr] = -INFINITY;
            }
        }

        // P = exp(s/8) raw; per-lane l accumulation
        #pragma unroll
        for (int nt = 0; nt < 4; ++nt) {
            #pragma unroll
            for (int rr = 0; rr < 4; ++rr) {
                const float pv = __expf(sc[nt][rr] * 0.125f);
                ls[rr] += pv;
                pl[(quad * 4 + rr) * PSTR + nt * 16 + col] =
                    __builtin_bit_cast(unsigned short, __float2bfloat16(pv));
            }
        }

        // P A-fragments (same-wave RAW via lgkmcnt)
        const bf16x8 pa0 = __builtin_bit_cast(bf16x8, p8[col * 9 + quad]);
        const bf16x8 pa1 = __builtin_bit_cast(bf16x8, p8[col * 9 + 4 + quad]);

        // O += P * V from LDS V
        #pragma unroll
        for (int dt = 0; dt < 4; ++dt) {
            const int dp = dt * 16 + col;
            const bf16x8 bv0 = __builtin_bit_cast(bf16x8, Vc[dp * 8 + ((quad + dp) & 7)]);
            const bf16x8 bv1 = __builtin_bit_cast(bf16x8, Vc[dp * 8 + ((4 + quad + dp) & 7)]);
            o[dt] = __builtin_amdgcn_mfma_f32_16x16x32_bf16(pa0, bv0, o[dt], 0, 0, 0);
            o[dt] = __builtin_amdgcn_mfma_f32_16x16x32_bf16(pa1, bv1, o[dt], 0, 0, 0);
        }
    }

    // l reduction over the 16 key-lanes
    #pragma unroll
    for (int rr = 0; rr < 4; ++rr) {
        #pragma unroll
        for (int msk = 1; msk < 16; msk <<= 1)
            ls[rr] += __shfl_xor(ls[rr], msk);
    }

    // store linear partials (Op, lp); combined by combine_kernel
    const int pbase = (tile * 4 + quarter) * 64 + wave * 16;
    #pragma unroll
    for (int dt = 0; dt < 4; ++dt)
        #pragma unroll
        for (int rr = 0; rr < 4; ++rr)
            Op[(size_t)(pbase + quad * 4 + rr) * D_QKV + dt * 16 + col] = o[dt][rr];
    if (col == 0) {
        #pragma unroll
        for (int rr = 0; rr < 4; ++rr)
            lp[pbase + quad * 4 + rr] = ls[rr];
    }
}

// ---------------------------------------------------------------------------
// Kernel C: combine 4 linear partials: out = sum(O_k) / sum(l_k).
// ---------------------------------------------------------------------------
__global__ __launch_bounds__(256) void combine_kernel(
    const float* __restrict__ Op, const float* __restrict__ lp,
    float* __restrict__ out)
{
    const int idx = blockIdx.x * 256 + threadIdx.x;   // 524288 = 8192*64
    const int qg = idx >> 6, d = idx & 63;
    const int tile = qg >> 6, qq = qg & 63;
    float s = 0.f, l = 0.f;
    #pragma unroll
    for (int k = 0; k < 4; ++k) {
        s += Op[(size_t)((tile * 4 + k) * 64 + qq) * D_QKV + d];
        l += lp[(tile * 4 + k) * 64 + qq];
    }
    out[(size_t)qg * D_QKV + d] = s / l;
}

// ---------------------------------------------------------------------------
extern "C" void kernel_launch(void* const* d_in, const int* in_sizes, int n_in,
                              void* d_out, int out_size, void* d_ws, size_t ws_size,
                              hipStream_t stream) {
    const float* x  = (const float*)d_in[0];
    const float* Wq = (const float*)d_in[1];
    const float* Wk = (const float*)d_in[2];
    const float* Wv = (const float*)d_in[3];
    float* out = (float*)d_out;

    char* ws = (char*)d_ws;
    bf16*  qb = (bf16*)(ws);                          // 1 MB
    bf16*  kb = (bf16*)(ws + (1u << 20));             // 1 MB
    bf16*  vt = (bf16*)(ws + (2u << 20));             // 1 MB
    bf16*  wt = (bf16*)(ws + (3u << 20));             // 384 KB
    float* Op = (float*)(ws + (4u << 20));            // 8 MB
    float* lp = (float*)(ws + (12u << 20));           // 128 KB

    wt_prep<<<48, 256, 0, stream>>>(Wq, Wk, Wv, wt);
    qkv_proj_mfma<<<256, 256, 0, stream>>>(x, wt, qb, kb, vt);
    attn_kernel<<<512, 256, 0, stream>>>(qb, kb, vt, Op, lp);
    combine_kernel<<<2048, 256, 0, stream>>>(Op, lp, out);
}